// Round 19
// baseline (80.477 us; speedup 1.0000x reference)
//
#include <hip/hip_runtime.h>

#define N_NODES 50000
#define N_EDGES 800000
#define D_INF 64
#define D_HIDF 128

#define NBUCKET ((N_NODES + 63) / 64)          // 782 buckets of 64 dst nodes
#define CHUNK 4096
#define NCHUNK ((N_EDGES + CHUNK - 1) / CHUNK) // 196 sort-fill blocks
#define CAP 4096                               // per-bucket binned capacity (avg 1024)

typedef __attribute__((ext_vector_type(8))) short bf16x8v;
typedef __attribute__((ext_vector_type(4))) float f32x4;

__device__ __forceinline__ ushort f2bf(float f) {
    unsigned int u = __builtin_bit_cast(unsigned int, f);
    u += 0x7FFF + ((u >> 16) & 1);  // RNE
    return (ushort)(u >> 16);
}
__device__ __forceinline__ float bf2f(ushort u) {
    return __builtin_bit_cast(float, ((unsigned int)u) << 16);
}
__device__ __forceinline__ float bflo(unsigned int w) {
    return __builtin_bit_cast(float, w << 16);
}
__device__ __forceinline__ float bfhi(unsigned int w) {
    return __builtin_bit_cast(float, w & 0xFFFF0000u);
}

// ---------------------------------------------------------------------------
// K1: fused prep — x->bf16 (+ zero row at N_NODES), weights->bf16 transposed,
// gcursor[b] = b*CAP.
// ---------------------------------------------------------------------------

#define CVT_N (N_NODES * D_INF / 8)   // 400000
#define PREP_N (D_INF * D_HIDF)       // 8192

__global__ void prep_kernel(const float* __restrict__ x, ushort* __restrict__ xb,
                            const float* __restrict__ W1, const float* __restrict__ W2,
                            ushort* __restrict__ w1tb, ushort* __restrict__ w2tb,
                            int* __restrict__ gcursor) {
    int gid = blockIdx.x * blockDim.x + threadIdx.x;
    if (gid < CVT_N) {
        float4 a = reinterpret_cast<const float4*>(x)[gid * 2];
        float4 b = reinterpret_cast<const float4*>(x)[gid * 2 + 1];
        ushort o[8] = {f2bf(a.x), f2bf(a.y), f2bf(a.z), f2bf(a.w),
                       f2bf(b.x), f2bf(b.y), f2bf(b.z), f2bf(b.w)};
        *reinterpret_cast<ulonglong2*>(xb + gid * 8) = *reinterpret_cast<ulonglong2*>(o);
    } else if (gid < CVT_N + PREP_N) {
        int i = gid - CVT_N;
        int j = i >> 6, l = i & 63;
        w1tb[i] = f2bf(W1[l * D_HIDF + j]);
        int d = i >> 7, jj = i & 127;
        w2tb[i] = f2bf(W2[jj * D_INF + d]);
    } else if (gid < CVT_N + PREP_N + NBUCKET) {
        int b = gid - CVT_N - PREP_N;
        gcursor[b] = b * CAP;
    } else if (gid < CVT_N + PREP_N + NBUCKET + 8) {
        int i = gid - CVT_N - PREP_N - NBUCKET;
        ulonglong2 z;
        z.x = 0; z.y = 0;
        *reinterpret_cast<ulonglong2*>(xb + (size_t)N_NODES * D_INF + i * 8) = z;  // zero row
    }
}

// ---------------------------------------------------------------------------
// K2: sort-fill (512 threads, 8 edges/thread). Edges read once into registers;
// counting-sort by bucket in LDS; contiguous-run writeout. pack=(dst<<16)|src.
// ---------------------------------------------------------------------------

__global__ void __launch_bounds__(512) sortfill_kernel(const int* __restrict__ src,
                                                       const int* __restrict__ dst,
                                                       int* __restrict__ gcursor,
                                                       unsigned int* __restrict__ binned) {
    __shared__ int cnt[NBUCKET];
    __shared__ int off[NBUCKET];
    __shared__ int cur[NBUCKET];
    __shared__ int gbase[NBUCKET];
    __shared__ unsigned int buf[CHUNK];
    __shared__ int wsum[8];

    int t = threadIdx.x;
    int lane = t & 63;
    int wv = t >> 6;          // 0..7
    int base = blockIdx.x * CHUNK;
    int chunk_n = min(CHUNK, N_EDGES - base);

    for (int i = t; i < NBUCKET; i += 512) cnt[i] = 0;
    __syncthreads();

    // pass 1: load edges into registers, count buckets
    unsigned int pkr[8];
    int bkt[8];
#pragma unroll
    for (int k = 0; k < 8; k++) {
        int e = base + k * 512 + t;
        bkt[k] = -1;
        pkr[k] = 0;
        if (e < N_EDGES) {
            int d = dst[e];
            int s = src[e];
            pkr[k] = ((unsigned int)d << 16) | (unsigned int)s;
            bkt[k] = d >> 6;
            atomicAdd(&cnt[bkt[k]], 1);
        }
    }
    __syncthreads();

    // scan (2 buckets/thread) + global reservation from gcursor (init b*CAP)
    {
        int b0 = t * 2;
        int v0 = (b0 < NBUCKET) ? cnt[b0] : 0;
        int v1 = (b0 + 1 < NBUCKET) ? cnt[b0 + 1] : 0;
        int s = v0 + v1;
        int incl = s;
#pragma unroll
        for (int o = 1; o < 64; o <<= 1) {
            int u = __shfl_up(incl, o);
            if (lane >= o) incl += u;
        }
        if (lane == 63) wsum[wv] = incl;
        __syncthreads();
        if (t == 0) {
#pragma unroll
            for (int w = 1; w < 8; w++) wsum[w] += wsum[w - 1];
        }
        __syncthreads();
        int run = ((wv > 0) ? wsum[wv - 1] : 0) + (incl - s);
        if (b0 < NBUCKET) {
            off[b0] = run;
            cur[b0] = run;
            if (v0 > 0) gbase[b0] = atomicAdd(&gcursor[b0], v0);
        }
        run += v0;
        if (b0 + 1 < NBUCKET) {
            off[b0 + 1] = run;
            cur[b0 + 1] = run;
            if (v1 > 0) gbase[b0 + 1] = atomicAdd(&gcursor[b0 + 1], v1);
        }
    }
    __syncthreads();

    // pass 2: place registers into LDS buffer sorted by bucket
#pragma unroll
    for (int k = 0; k < 8; k++) {
        if (bkt[k] >= 0) {
            int r = atomicAdd(&cur[bkt[k]], 1);
            buf[r] = pkr[k];
        }
    }
    __syncthreads();

    // pass 3: contiguous-run writeout (capacity-guarded)
#pragma unroll
    for (int k = 0; k < CHUNK / 512; k++) {
        int slot = k * 512 + t;
        if (slot < chunk_n) {
            unsigned int pk = buf[slot];
            int b = pk >> 22;
            int idx = gbase[b] + (slot - off[b]);
            if (idx < (b + 1) * CAP) binned[idx] = pk;
        }
    }
}

// ---------------------------------------------------------------------------
// K3 (MEGA): one block per bucket, 1024 threads = 16 waves.
// Phase A: node-sort the bucket segment in LDS.
// Phase B: gather — wave's 4 nodes processed CONCURRENTLY: 16 loads in flight
//          (4 nodes x 4 sub-batches), dummy zero-row loads for finished nodes.
// Phase C: MLP — 16 waves split both GEMMs; weights direct from global/L2.
// ---------------------------------------------------------------------------

#define AT_LD 72
#define HT_LD 136

__global__ void __launch_bounds__(1024) mega_kernel(
    const ushort* __restrict__ xb, const unsigned int* __restrict__ binned,
    const int* __restrict__ gcursor,
    const ushort* __restrict__ w1tb, const float* __restrict__ b1v,
    const ushort* __restrict__ w2tb, const float* __restrict__ b2v,
    float* __restrict__ out)
{
    __shared__ unsigned int seg[CAP];                   // 16 KB
    __shared__ unsigned int sorted[CAP + 16];           // 16 KB (+slack)
    __shared__ __align__(16) ushort atile[64 * AT_LD];  //  9.2 KB
    __shared__ __align__(16) ushort htile[64 * HT_LD];  // 17.4 KB
    __shared__ int c64[64];
    __shared__ int rb[65];
    __shared__ int o64[64];

    int t = threadIdx.x;
    int lane = t & 63;
    int wv = t >> 6;           // 0..15
    int b = blockIdx.x;
    int beg = b * CAP;
    int cnt = min(gcursor[b] - beg, CAP);
    int nb = b * 64;
    int nvalid = min(64, N_NODES - nb);

    if (t < 64) c64[t] = 0;
    __syncthreads();

    // ---- Phase A: in-LDS counting sort by node ----
    for (int i = t; i < cnt; i += 1024) {
        unsigned int pk = binned[beg + i];
        seg[i] = pk;
        atomicAdd(&c64[(pk >> 16) & 63], 1);
    }
    __syncthreads();
    if (t < 64) {
        int v = c64[t];
        int incl = v;
#pragma unroll
        for (int off = 1; off < 64; off <<= 1) {
            int u = __shfl_up(incl, off);
            if (t >= off) incl += u;
        }
        rb[t] = incl - v;
        o64[t] = incl - v;
        if (t == 63) rb[64] = incl;
    }
    __syncthreads();
    for (int i = t; i < cnt; i += 1024) {
        unsigned int pk = seg[i];
        int pos = atomicAdd(&o64[(pk >> 16) & 63], 1);
        sorted[pos] = pk;
    }
    __syncthreads();

    // ---- Phase B: gather (wave w -> nodes 4w..4w+3, CONCURRENT) ----
    // 16-lane group g4 handles one edge per sub-batch; lane covers features
    // f4*4..f4*4+3 (dwordx2). 4 nodes x 4 sub-batches = 16 loads in flight.
    int g4 = lane >> 4;        // 0..3
    int f4 = lane & 15;        // feature-quad index
    int n0 = wv * 4;

    float acc[4][4] = {{0.f, 0.f, 0.f, 0.f}, {0.f, 0.f, 0.f, 0.f},
                       {0.f, 0.f, 0.f, 0.f}, {0.f, 0.f, 0.f, 0.f}};
    int e[4], E[4];
#pragma unroll
    for (int k = 0; k < 4; k++) {
        e[k] = rb[n0 + k];
        E[k] = rb[n0 + k + 1];
    }

    while (e[0] < E[0] || e[1] < E[1] || e[2] < E[2] || e[3] < E[3]) {
        uint2 v[4][4];
#pragma unroll
        for (int k = 0; k < 4; k++) {
#pragma unroll
            for (int s = 0; s < 4; s++) {
                int idx = e[k] + s * 4 + g4;
                unsigned int pk = (idx < E[k]) ? sorted[idx] : (unsigned int)N_NODES;
                v[k][s] = *reinterpret_cast<const uint2*>(
                    &xb[(size_t)(pk & 0xFFFFu) * D_INF + f4 * 4]);
            }
        }
#pragma unroll
        for (int k = 0; k < 4; k++) {
#pragma unroll
            for (int s = 0; s < 4; s++) {
                acc[k][0] += bflo(v[k][s].x);
                acc[k][1] += bfhi(v[k][s].x);
                acc[k][2] += bflo(v[k][s].y);
                acc[k][3] += bfhi(v[k][s].y);
            }
            e[k] += 16;
        }
    }

    // merge 4 lane groups (2 levels) per node, per accumulator
#pragma unroll
    for (int k = 0; k < 4; k++) {
#pragma unroll
        for (int i = 0; i < 4; i++) {
            acc[k][i] += __shfl_xor(acc[k][i], 16);
            acc[k][i] += __shfl_xor(acc[k][i], 32);
        }
    }
    if (g4 == 0) {
#pragma unroll
        for (int k = 0; k < 4; k++) {
            int n = n0 + k;
            if (n < nvalid) {  // self term
                uint2 v = *reinterpret_cast<const uint2*>(
                    &xb[(size_t)(nb + n) * D_INF + f4 * 4]);
                acc[k][0] += bflo(v.x);
                acc[k][1] += bfhi(v.x);
                acc[k][2] += bflo(v.y);
                acc[k][3] += bfhi(v.y);
            }
            unsigned int w0 = (unsigned int)f2bf(acc[k][0]) |
                              ((unsigned int)f2bf(acc[k][1]) << 16);
            unsigned int w1 = (unsigned int)f2bf(acc[k][2]) |
                              ((unsigned int)f2bf(acc[k][3]) << 16);
            *reinterpret_cast<uint2*>(&atile[n * AT_LD + f4 * 4]) = make_uint2(w0, w1);
        }
    }
    __syncthreads();

    // ---- Phase C: MLP ----
    int q = lane >> 4;
    int m = lane & 15;
    int mt = wv & 3;          // M-tile 0..3
    int arow = mt * 16 + m;
    int hrow0 = mt * 16 + q * 4;

    bf16x8v a0v = *reinterpret_cast<const bf16x8v*>(&atile[arow * AT_LD + q * 8]);
    bf16x8v a1v = *reinterpret_cast<const bf16x8v*>(&atile[arow * AT_LD + 32 + q * 8]);
    int jt0 = (wv >> 2) * 2;
#pragma unroll
    for (int jj = 0; jj < 2; jj++) {
        int j = (jt0 + jj) * 16 + m;
        bf16x8v bf0 = *reinterpret_cast<const bf16x8v*>(w1tb + j * D_INF + q * 8);
        bf16x8v bf1 = *reinterpret_cast<const bf16x8v*>(w1tb + j * D_INF + 32 + q * 8);
        f32x4 acc2 = {0.f, 0.f, 0.f, 0.f};
        acc2 = __builtin_amdgcn_mfma_f32_16x16x32_bf16(a0v, bf0, acc2, 0, 0, 0);
        acc2 = __builtin_amdgcn_mfma_f32_16x16x32_bf16(a1v, bf1, acc2, 0, 0, 0);
        float bv = b1v[j];
#pragma unroll
        for (int r = 0; r < 4; r++) {
            float hv = fmaxf(acc2[r] + bv, 0.f);
            htile[(hrow0 + r) * HT_LD + j] = f2bf(hv);
        }
    }
    __syncthreads();

    bf16x8v ha0 = *reinterpret_cast<const bf16x8v*>(&htile[arow * HT_LD + 0 * 32 + q * 8]);
    bf16x8v ha1 = *reinterpret_cast<const bf16x8v*>(&htile[arow * HT_LD + 1 * 32 + q * 8]);
    bf16x8v ha2 = *reinterpret_cast<const bf16x8v*>(&htile[arow * HT_LD + 2 * 32 + q * 8]);
    bf16x8v ha3 = *reinterpret_cast<const bf16x8v*>(&htile[arow * HT_LD + 3 * 32 + q * 8]);
    {
        int d = (wv >> 2) * 16 + m;
        bf16x8v bw0 = *reinterpret_cast<const bf16x8v*>(w2tb + d * D_HIDF + 0 * 32 + q * 8);
        bf16x8v bw1 = *reinterpret_cast<const bf16x8v*>(w2tb + d * D_HIDF + 1 * 32 + q * 8);
        bf16x8v bw2 = *reinterpret_cast<const bf16x8v*>(w2tb + d * D_HIDF + 2 * 32 + q * 8);
        bf16x8v bw3 = *reinterpret_cast<const bf16x8v*>(w2tb + d * D_HIDF + 3 * 32 + q * 8);
        f32x4 acc2 = {0.f, 0.f, 0.f, 0.f};
        acc2 = __builtin_amdgcn_mfma_f32_16x16x32_bf16(ha0, bw0, acc2, 0, 0, 0);
        acc2 = __builtin_amdgcn_mfma_f32_16x16x32_bf16(ha1, bw1, acc2, 0, 0, 0);
        acc2 = __builtin_amdgcn_mfma_f32_16x16x32_bf16(ha2, bw2, acc2, 0, 0, 0);
        acc2 = __builtin_amdgcn_mfma_f32_16x16x32_bf16(ha3, bw3, acc2, 0, 0, 0);
        float bv = b2v[d];
#pragma unroll
        for (int r = 0; r < 4; r++) {
            int node = nb + hrow0 + r;
            if (node < N_NODES) out[(size_t)node * D_INF + d] = acc2[r] + bv;
        }
    }
}

// ---------------------------------------------------------------------------
// Fallback path (ws too small): atomic scatter + standalone MLP (proven r8).
// ---------------------------------------------------------------------------

#define W1_LD 72
#define W2_LD 136

__global__ void __launch_bounds__(256) mlp_mfma_kernel(
    const ushort* __restrict__ aggb, const ushort* __restrict__ w1tb,
    const float* __restrict__ b1v, const ushort* __restrict__ w2tb,
    const float* __restrict__ b2v, float* __restrict__ out)
{
    __shared__ __align__(16) ushort atile[64 * AT_LD];
    __shared__ __align__(16) ushort w1s[128 * W1_LD];
    __shared__ __align__(16) ushort w2s[64 * W2_LD];
    __shared__ __align__(16) ushort htile[64 * HT_LD];

    int tid = threadIdx.x;
    int lane = tid & 63;
    int wv = tid >> 6;
    int nb = blockIdx.x * 64;

#pragma unroll
    for (int c = 0; c < 2; c++) {
        int chunk = tid + c * 256;
        int row = chunk >> 3;
        int col = (chunk & 7) * 8;
        ulonglong2 v;
        v.x = 0; v.y = 0;
        if (nb + row < N_NODES)
            v = *reinterpret_cast<const ulonglong2*>(aggb + (size_t)(nb + row) * D_INF + col);
        *reinterpret_cast<ulonglong2*>(&atile[row * AT_LD + col]) = v;
    }
#pragma unroll
    for (int c = 0; c < 4; c++) {
        int chunk = tid + c * 256;
        int row = chunk >> 3;
        int col = (chunk & 7) * 8;
        *reinterpret_cast<ulonglong2*>(&w1s[row * W1_LD + col]) =
            *reinterpret_cast<const ulonglong2*>(w1tb + row * 64 + col);
    }
#pragma unroll
    for (int c = 0; c < 4; c++) {
        int chunk = tid + c * 256;
        int row = chunk >> 4;
        int col = (chunk & 15) * 8;
        *reinterpret_cast<ulonglong2*>(&w2s[row * W2_LD + col]) =
            *reinterpret_cast<const ulonglong2*>(w2tb + row * 128 + col);
    }
    __syncthreads();

    int q = lane >> 4;
    int m = lane & 15;
    int arow = wv * 16 + m;
    int hrow0 = wv * 16 + q * 4;

    bf16x8v a0 = *reinterpret_cast<const bf16x8v*>(&atile[arow * AT_LD + q * 8]);
    bf16x8v a1 = *reinterpret_cast<const bf16x8v*>(&atile[arow * AT_LD + 32 + q * 8]);
#pragma unroll
    for (int jt = 0; jt < 8; jt++) {
        int j = jt * 16 + m;
        bf16x8v bf0 = *reinterpret_cast<const bf16x8v*>(&w1s[j * W1_LD + q * 8]);
        bf16x8v bf1 = *reinterpret_cast<const bf16x8v*>(&w1s[j * W1_LD + 32 + q * 8]);
        f32x4 acc = {0.f, 0.f, 0.f, 0.f};
        acc = __builtin_amdgcn_mfma_f32_16x16x32_bf16(a0, bf0, acc, 0, 0, 0);
        acc = __builtin_amdgcn_mfma_f32_16x16x32_bf16(a1, bf1, acc, 0, 0, 0);
        float bv = b1v[j];
#pragma unroll
        for (int r = 0; r < 4; r++) {
            float hv = fmaxf(acc[r] + bv, 0.f);
            htile[(hrow0 + r) * HT_LD + j] = f2bf(hv);
        }
    }

    bf16x8v ha0 = *reinterpret_cast<const bf16x8v*>(&htile[arow * HT_LD + 0 * 32 + q * 8]);
    bf16x8v ha1 = *reinterpret_cast<const bf16x8v*>(&htile[arow * HT_LD + 1 * 32 + q * 8]);
    bf16x8v ha2 = *reinterpret_cast<const bf16x8v*>(&htile[arow * HT_LD + 2 * 32 + q * 8]);
    bf16x8v ha3 = *reinterpret_cast<const bf16x8v*>(&htile[arow * HT_LD + 3 * 32 + q * 8]);
#pragma unroll
    for (int dt = 0; dt < 4; dt++) {
        int d = dt * 16 + m;
        f32x4 acc = {0.f, 0.f, 0.f, 0.f};
        bf16x8v bw0 = *reinterpret_cast<const bf16x8v*>(&w2s[d * W2_LD + 0 * 32 + q * 8]);
        bf16x8v bw1 = *reinterpret_cast<const bf16x8v*>(&w2s[d * W2_LD + 1 * 32 + q * 8]);
        bf16x8v bw2 = *reinterpret_cast<const bf16x8v*>(&w2s[d * W2_LD + 2 * 32 + q * 8]);
        bf16x8v bw3 = *reinterpret_cast<const bf16x8v*>(&w2s[d * W2_LD + 3 * 32 + q * 8]);
        acc = __builtin_amdgcn_mfma_f32_16x16x32_bf16(ha0, bw0, acc, 0, 0, 0);
        acc = __builtin_amdgcn_mfma_f32_16x16x32_bf16(ha1, bw1, acc, 0, 0, 0);
        acc = __builtin_amdgcn_mfma_f32_16x16x32_bf16(ha2, bw2, acc, 0, 0, 0);
        acc = __builtin_amdgcn_mfma_f32_16x16x32_bf16(ha3, bw3, acc, 0, 0, 0);
        float bv = b2v[d];
#pragma unroll
        for (int r = 0; r < 4; r++) {
            int node = nb + hrow0 + r;
            if (node < N_NODES) out[(size_t)node * D_INF + d] = acc[r] + bv;
        }
    }
}

__global__ void init_agg_kernel(const float* __restrict__ x, float* __restrict__ agg) {
    int i = blockIdx.x * blockDim.x + threadIdx.x;
    int n4 = N_NODES * D_INF / 4;
    if (i < n4) {
        reinterpret_cast<float4*>(agg)[i] = reinterpret_cast<const float4*>(x)[i];
    }
}

__global__ void scatter_kernel(const float* __restrict__ x,
                               const int* __restrict__ src,
                               const int* __restrict__ dst,
                               float* __restrict__ agg) {
    int tid = blockIdx.x * blockDim.x + threadIdx.x;
    int e = tid >> 6;
    int d = tid & 63;
    if (e < N_EDGES) {
        atomicAdd(&agg[(size_t)dst[e] * D_INF + d], x[(size_t)src[e] * D_INF + d]);
    }
}

__global__ void cvt_agg_kernel(const float* __restrict__ agg32, ushort* __restrict__ aggb) {
    int i = blockIdx.x * blockDim.x + threadIdx.x;
    if (i < N_NODES * D_INF) aggb[i] = f2bf(agg32[i]);
}

__global__ void prep_weights_only_kernel(const float* __restrict__ W1,
                                         const float* __restrict__ W2,
                                         ushort* __restrict__ w1tb,
                                         ushort* __restrict__ w2tb) {
    int i = blockIdx.x * blockDim.x + threadIdx.x;
    if (i < D_INF * D_HIDF) {
        int j = i >> 6, l = i & 63;
        w1tb[i] = f2bf(W1[l * D_HIDF + j]);
        int d = i >> 7, jj = i & 127;
        w2tb[i] = f2bf(W2[jj * D_INF + d]);
    }
}

// ---------------------------------------------------------------------------

extern "C" void kernel_launch(void* const* d_in, const int* in_sizes, int n_in,
                              void* d_out, int out_size, void* d_ws, size_t ws_size,
                              hipStream_t stream) {
    const float* x   = (const float*)d_in[0];
    const int* edge  = (const int*)d_in[1];   // [2, E]: src = edge, dst = edge + E
    const float* W1  = (const float*)d_in[2];
    const float* b1  = (const float*)d_in[3];
    const float* W2  = (const float*)d_in[4];
    const float* b2  = (const float*)d_in[5];
    float* out       = (float*)d_out;

    const int* src = edge;
    const int* dst = edge + N_EDGES;

    // Workspace layout (fast path ~19.3 MB):
    //   w1tb / w2tb : 8192 bf16 each (32 KB)
    //   xb     : (N+1)*64 bf16 (6.4 MB, incl. zero row at N_NODES)
    //   gcursor: NBUCKET ints
    //   binned : NBUCKET*CAP uints (12.8 MB)
    //   fallback overlay: agg32 (f32, at xb) + aggb (bf16, after binned)
    ushort* w1tb   = (ushort*)d_ws;
    ushort* w2tb   = w1tb + D_INF * D_HIDF;
    ushort* xb     = w2tb + D_INF * D_HIDF;
    int* gcursor   = (int*)(xb + (size_t)(N_NODES + 1) * D_INF);
    unsigned int* binned = (unsigned int*)(gcursor + NBUCKET);
    float* agg32   = (float*)xb;
    ushort* aggb   = (ushort*)(binned + (size_t)NBUCKET * CAP);

    size_t needed_full = (uintptr_t)(binned + (size_t)NBUCKET * CAP) - (uintptr_t)d_ws;
    size_t needed_fb   = (uintptr_t)(aggb + (size_t)N_NODES * D_INF) - (uintptr_t)d_ws;

    if (ws_size >= needed_full) {
        int prep_total = CVT_N + PREP_N + NBUCKET + 8;
        prep_kernel<<<(prep_total + 255) / 256, 256, 0, stream>>>(
            x, xb, W1, W2, w1tb, w2tb, gcursor);
        sortfill_kernel<<<NCHUNK, 512, 0, stream>>>(src, dst, gcursor, binned);
        mega_kernel<<<NBUCKET, 1024, 0, stream>>>(
            xb, binned, gcursor, w1tb, b1, w2tb, b2, out);
    } else if (ws_size >= needed_fb) {
        prep_weights_only_kernel<<<(PREP_N + 255) / 256, 256, 0, stream>>>(W1, W2, w1tb, w2tb);
        int n4 = N_NODES * D_INF / 4;
        init_agg_kernel<<<(n4 + 255) / 256, 256, 0, stream>>>(x, agg32);
        int work = N_EDGES * D_INF;
        scatter_kernel<<<(work + 255) / 256, 256, 0, stream>>>(x, src, dst, agg32);
        cvt_agg_kernel<<<(N_NODES * D_INF + 255) / 256, 256, 0, stream>>>(agg32, aggb);
        mlp_mfma_kernel<<<(N_NODES + 63) / 64, 256, 0, stream>>>(aggb, w1tb, b1, w2tb, b2, out);
    }
}

// Round 20
// 64.302 us; speedup vs baseline: 1.2515x; 1.2515x over previous
//
#include <hip/hip_runtime.h>

#define N_NODES 50000
#define N_EDGES 800000
#define D_INF 64
#define D_HIDF 128

#define NBUCKET ((N_NODES + 63) / 64)          // 782 buckets of 64 dst nodes
#define CHUNK 4096
#define NCHUNK ((N_EDGES + CHUNK - 1) / CHUNK) // 196 sort-fill blocks
#define CAP 4096                               // per-bucket binned capacity (avg 1024)

#define CVT_N (N_NODES * D_INF / 8)   // 400000
#define PREP_N (D_INF * D_HIDF)       // 8192
#define CVT_TOTAL (CVT_N + PREP_N + 8)
#define CVT_BLKS ((CVT_TOTAL + 511) / 512)     // 798

typedef __attribute__((ext_vector_type(8))) short bf16x8v;
typedef __attribute__((ext_vector_type(4))) float f32x4;

__device__ __forceinline__ ushort f2bf(float f) {
    unsigned int u = __builtin_bit_cast(unsigned int, f);
    u += 0x7FFF + ((u >> 16) & 1);  // RNE
    return (ushort)(u >> 16);
}
__device__ __forceinline__ float bf2f(ushort u) {
    return __builtin_bit_cast(float, ((unsigned int)u) << 16);
}
__device__ __forceinline__ float bflo(unsigned int w) {
    return __builtin_bit_cast(float, w << 16);
}
__device__ __forceinline__ float bfhi(unsigned int w) {
    return __builtin_bit_cast(float, w & 0xFFFF0000u);
}

// ---------------------------------------------------------------------------
// K1 (tiny): gcursor[b] = b*CAP
// ---------------------------------------------------------------------------

__global__ void init_gcursor_kernel(int* __restrict__ gcursor) {
    int i = blockIdx.x * blockDim.x + threadIdx.x;
    if (i < NBUCKET) gcursor[i] = i * CAP;
}

// ---------------------------------------------------------------------------
// K2: fused sortfill + cvt. Blocks [0,NCHUNK) counting-sort their 4096-edge
// chunk into capacity-partitioned binned[] (pack=(dst<<16)|src). Blocks
// [NCHUNK,..) convert x->bf16 (+zero row) and weights->bf16 transposed —
// independent work overlapped in one dispatch.
// ---------------------------------------------------------------------------

__global__ void __launch_bounds__(512) sortfill_cvt_kernel(
    const int* __restrict__ src, const int* __restrict__ dst,
    int* __restrict__ gcursor, unsigned int* __restrict__ binned,
    const float* __restrict__ x, ushort* __restrict__ xb,
    const float* __restrict__ W1, const float* __restrict__ W2,
    ushort* __restrict__ w1tb, ushort* __restrict__ w2tb)
{
    if (blockIdx.x >= NCHUNK) {
        // ---- cvt part ----
        int gid = (blockIdx.x - NCHUNK) * 512 + threadIdx.x;
        if (gid < CVT_N) {
            float4 a = reinterpret_cast<const float4*>(x)[gid * 2];
            float4 b = reinterpret_cast<const float4*>(x)[gid * 2 + 1];
            ushort o[8] = {f2bf(a.x), f2bf(a.y), f2bf(a.z), f2bf(a.w),
                           f2bf(b.x), f2bf(b.y), f2bf(b.z), f2bf(b.w)};
            *reinterpret_cast<ulonglong2*>(xb + gid * 8) = *reinterpret_cast<ulonglong2*>(o);
        } else if (gid < CVT_N + PREP_N) {
            int i = gid - CVT_N;
            int j = i >> 6, l = i & 63;
            w1tb[i] = f2bf(W1[l * D_HIDF + j]);
            int d = i >> 7, jj = i & 127;
            w2tb[i] = f2bf(W2[jj * D_INF + d]);
        } else if (gid < CVT_TOTAL) {
            int i = gid - CVT_N - PREP_N;
            ulonglong2 z;
            z.x = 0; z.y = 0;
            *reinterpret_cast<ulonglong2*>(xb + (size_t)N_NODES * D_INF + i * 8) = z;
        }
        return;
    }

    // ---- sortfill part ----
    __shared__ int cnt[NBUCKET];
    __shared__ int off[NBUCKET];
    __shared__ int cur[NBUCKET];
    __shared__ int gbase[NBUCKET];
    __shared__ unsigned int buf[CHUNK];
    __shared__ int wsum[8];

    int t = threadIdx.x;
    int lane = t & 63;
    int wv = t >> 6;          // 0..7
    int base = blockIdx.x * CHUNK;
    int chunk_n = min(CHUNK, N_EDGES - base);

    for (int i = t; i < NBUCKET; i += 512) cnt[i] = 0;
    __syncthreads();

    // pass 1: load edges into registers, count buckets
    unsigned int pkr[8];
    int bkt[8];
#pragma unroll
    for (int k = 0; k < 8; k++) {
        int e = base + k * 512 + t;
        bkt[k] = -1;
        pkr[k] = 0;
        if (e < N_EDGES) {
            int d = dst[e];
            int s = src[e];
            pkr[k] = ((unsigned int)d << 16) | (unsigned int)s;
            bkt[k] = d >> 6;
            atomicAdd(&cnt[bkt[k]], 1);
        }
    }
    __syncthreads();

    // scan (2 buckets/thread) + global reservation from gcursor (init b*CAP)
    {
        int b0 = t * 2;
        int v0 = (b0 < NBUCKET) ? cnt[b0] : 0;
        int v1 = (b0 + 1 < NBUCKET) ? cnt[b0 + 1] : 0;
        int s = v0 + v1;
        int incl = s;
#pragma unroll
        for (int o = 1; o < 64; o <<= 1) {
            int u = __shfl_up(incl, o);
            if (lane >= o) incl += u;
        }
        if (lane == 63) wsum[wv] = incl;
        __syncthreads();
        if (t == 0) {
#pragma unroll
            for (int w = 1; w < 8; w++) wsum[w] += wsum[w - 1];
        }
        __syncthreads();
        int run = ((wv > 0) ? wsum[wv - 1] : 0) + (incl - s);
        if (b0 < NBUCKET) {
            off[b0] = run;
            cur[b0] = run;
            if (v0 > 0) gbase[b0] = atomicAdd(&gcursor[b0], v0);
        }
        run += v0;
        if (b0 + 1 < NBUCKET) {
            off[b0 + 1] = run;
            cur[b0 + 1] = run;
            if (v1 > 0) gbase[b0 + 1] = atomicAdd(&gcursor[b0 + 1], v1);
        }
    }
    __syncthreads();

    // pass 2: place registers into LDS buffer sorted by bucket
#pragma unroll
    for (int k = 0; k < 8; k++) {
        if (bkt[k] >= 0) {
            int r = atomicAdd(&cur[bkt[k]], 1);
            buf[r] = pkr[k];
        }
    }
    __syncthreads();

    // pass 3: contiguous-run writeout (capacity-guarded)
#pragma unroll
    for (int k = 0; k < CHUNK / 512; k++) {
        int slot = k * 512 + t;
        if (slot < chunk_n) {
            unsigned int pk = buf[slot];
            int b = pk >> 22;
            int idx = gbase[b] + (slot - off[b]);
            if (idx < (b + 1) * CAP) binned[idx] = pk;
        }
    }
}

// ---------------------------------------------------------------------------
// K3 (MEGA): one block per bucket, 1024 threads = 16 waves. (r18 proven)
// Phase A: node-sort the bucket segment in LDS.
// Phase B: gather — per node, uniform loop, 4 unconditional loads/iter
//          (dummy zero-row for over-end slots), unroll 2 => 8 in flight.
// Phase C: MLP — 16 waves split both GEMMs; weights direct from global/L2.
// ---------------------------------------------------------------------------

#define AT_LD 72
#define HT_LD 136

__global__ void __launch_bounds__(1024) mega_kernel(
    const ushort* __restrict__ xb, const unsigned int* __restrict__ binned,
    const int* __restrict__ gcursor,
    const ushort* __restrict__ w1tb, const float* __restrict__ b1v,
    const ushort* __restrict__ w2tb, const float* __restrict__ b2v,
    float* __restrict__ out)
{
    __shared__ unsigned int seg[CAP];                   // 16 KB
    __shared__ unsigned int sorted[CAP + 16];           // 16 KB (+slack)
    __shared__ __align__(16) ushort atile[64 * AT_LD];  //  9.2 KB
    __shared__ __align__(16) ushort htile[64 * HT_LD];  // 17.4 KB
    __shared__ int c64[64];
    __shared__ int rb[65];
    __shared__ int o64[64];

    int t = threadIdx.x;
    int lane = t & 63;
    int wv = t >> 6;           // 0..15
    int b = blockIdx.x;
    int beg = b * CAP;
    int cnt = min(gcursor[b] - beg, CAP);
    int nb = b * 64;
    int nvalid = min(64, N_NODES - nb);

    if (t < 64) c64[t] = 0;
    __syncthreads();

    // ---- Phase A: in-LDS counting sort by node ----
    for (int i = t; i < cnt; i += 1024) {
        unsigned int pk = binned[beg + i];
        seg[i] = pk;
        atomicAdd(&c64[(pk >> 16) & 63], 1);
    }
    __syncthreads();
    if (t < 64) {
        int v = c64[t];
        int incl = v;
#pragma unroll
        for (int off = 1; off < 64; off <<= 1) {
            int u = __shfl_up(incl, off);
            if (t >= off) incl += u;
        }
        rb[t] = incl - v;
        o64[t] = incl - v;
        if (t == 63) rb[64] = incl;
    }
    __syncthreads();
    for (int i = t; i < cnt; i += 1024) {
        unsigned int pk = seg[i];
        int pos = atomicAdd(&o64[(pk >> 16) & 63], 1);
        sorted[pos] = pk;
    }
    __syncthreads();

    // ---- Phase B: gather (wave w -> nodes 4w..4w+3) ----
    // 16-lane group g4 handles one edge per 4-edge sub-batch; lane covers
    // features f4*4..f4*4+3 (dwordx2). Over-end slots load the zero row.
    int g4 = lane >> 4;        // 0..3
    int f4 = lane & 15;        // feature-quad index
#pragma unroll
    for (int k = 0; k < 4; k++) {
        int n = wv * 4 + k;
        float a0 = 0.f, a1 = 0.f, a2 = 0.f, a3 = 0.f;
        if (n < nvalid) {
            int e = rb[n];
            int end = rb[n + 1];
#pragma unroll 2
            for (; e < end; e += 16) {
                int i0 = e + 0 + g4;
                int i1 = e + 4 + g4;
                int i2 = e + 8 + g4;
                int i3 = e + 12 + g4;
                unsigned int pk0 = (i0 < end) ? sorted[i0] : (unsigned int)N_NODES;
                unsigned int pk1 = (i1 < end) ? sorted[i1] : (unsigned int)N_NODES;
                unsigned int pk2 = (i2 < end) ? sorted[i2] : (unsigned int)N_NODES;
                unsigned int pk3 = (i3 < end) ? sorted[i3] : (unsigned int)N_NODES;
                uint2 v0 = *reinterpret_cast<const uint2*>(
                    &xb[(size_t)(pk0 & 0xFFFFu) * D_INF + f4 * 4]);
                uint2 v1 = *reinterpret_cast<const uint2*>(
                    &xb[(size_t)(pk1 & 0xFFFFu) * D_INF + f4 * 4]);
                uint2 v2 = *reinterpret_cast<const uint2*>(
                    &xb[(size_t)(pk2 & 0xFFFFu) * D_INF + f4 * 4]);
                uint2 v3 = *reinterpret_cast<const uint2*>(
                    &xb[(size_t)(pk3 & 0xFFFFu) * D_INF + f4 * 4]);
                a0 += bflo(v0.x); a1 += bfhi(v0.x); a2 += bflo(v0.y); a3 += bfhi(v0.y);
                a0 += bflo(v1.x); a1 += bfhi(v1.x); a2 += bflo(v1.y); a3 += bfhi(v1.y);
                a0 += bflo(v2.x); a1 += bfhi(v2.x); a2 += bflo(v2.y); a3 += bfhi(v2.y);
                a0 += bflo(v3.x); a1 += bfhi(v3.x); a2 += bflo(v3.y); a3 += bfhi(v3.y);
            }
            // merge 4 lane groups (2 levels)
            a0 += __shfl_xor(a0, 16); a0 += __shfl_xor(a0, 32);
            a1 += __shfl_xor(a1, 16); a1 += __shfl_xor(a1, 32);
            a2 += __shfl_xor(a2, 16); a2 += __shfl_xor(a2, 32);
            a3 += __shfl_xor(a3, 16); a3 += __shfl_xor(a3, 32);
        }
        if (g4 == 0 && n < 64) {
            if (n < nvalid) {  // self term
                uint2 v = *reinterpret_cast<const uint2*>(
                    &xb[(size_t)(nb + n) * D_INF + f4 * 4]);
                a0 += bflo(v.x); a1 += bfhi(v.x);
                a2 += bflo(v.y); a3 += bfhi(v.y);
            }
            unsigned int w0 = (unsigned int)f2bf(a0) | ((unsigned int)f2bf(a1) << 16);
            unsigned int w1 = (unsigned int)f2bf(a2) | ((unsigned int)f2bf(a3) << 16);
            *reinterpret_cast<uint2*>(&atile[n * AT_LD + f4 * 4]) = make_uint2(w0, w1);
        }
    }
    __syncthreads();

    // ---- Phase C: MLP ----
    int q = lane >> 4;
    int m = lane & 15;
    int mt = wv & 3;          // M-tile 0..3
    int arow = mt * 16 + m;
    int hrow0 = mt * 16 + q * 4;

    bf16x8v a0v = *reinterpret_cast<const bf16x8v*>(&atile[arow * AT_LD + q * 8]);
    bf16x8v a1v = *reinterpret_cast<const bf16x8v*>(&atile[arow * AT_LD + 32 + q * 8]);
    int jt0 = (wv >> 2) * 2;
#pragma unroll
    for (int jj = 0; jj < 2; jj++) {
        int j = (jt0 + jj) * 16 + m;
        bf16x8v bf0 = *reinterpret_cast<const bf16x8v*>(w1tb + j * D_INF + q * 8);
        bf16x8v bf1 = *reinterpret_cast<const bf16x8v*>(w1tb + j * D_INF + 32 + q * 8);
        f32x4 acc = {0.f, 0.f, 0.f, 0.f};
        acc = __builtin_amdgcn_mfma_f32_16x16x32_bf16(a0v, bf0, acc, 0, 0, 0);
        acc = __builtin_amdgcn_mfma_f32_16x16x32_bf16(a1v, bf1, acc, 0, 0, 0);
        float bv = b1v[j];
#pragma unroll
        for (int r = 0; r < 4; r++) {
            float hv = fmaxf(acc[r] + bv, 0.f);
            htile[(hrow0 + r) * HT_LD + j] = f2bf(hv);
        }
    }
    __syncthreads();

    bf16x8v ha0 = *reinterpret_cast<const bf16x8v*>(&htile[arow * HT_LD + 0 * 32 + q * 8]);
    bf16x8v ha1 = *reinterpret_cast<const bf16x8v*>(&htile[arow * HT_LD + 1 * 32 + q * 8]);
    bf16x8v ha2 = *reinterpret_cast<const bf16x8v*>(&htile[arow * HT_LD + 2 * 32 + q * 8]);
    bf16x8v ha3 = *reinterpret_cast<const bf16x8v*>(&htile[arow * HT_LD + 3 * 32 + q * 8]);
    {
        int d = (wv >> 2) * 16 + m;
        bf16x8v bw0 = *reinterpret_cast<const bf16x8v*>(w2tb + d * D_HIDF + 0 * 32 + q * 8);
        bf16x8v bw1 = *reinterpret_cast<const bf16x8v*>(w2tb + d * D_HIDF + 1 * 32 + q * 8);
        bf16x8v bw2 = *reinterpret_cast<const bf16x8v*>(w2tb + d * D_HIDF + 2 * 32 + q * 8);
        bf16x8v bw3 = *reinterpret_cast<const bf16x8v*>(w2tb + d * D_HIDF + 3 * 32 + q * 8);
        f32x4 acc = {0.f, 0.f, 0.f, 0.f};
        acc = __builtin_amdgcn_mfma_f32_16x16x32_bf16(ha0, bw0, acc, 0, 0, 0);
        acc = __builtin_amdgcn_mfma_f32_16x16x32_bf16(ha1, bw1, acc, 0, 0, 0);
        acc = __builtin_amdgcn_mfma_f32_16x16x32_bf16(ha2, bw2, acc, 0, 0, 0);
        acc = __builtin_amdgcn_mfma_f32_16x16x32_bf16(ha3, bw3, acc, 0, 0, 0);
        float bv = b2v[d];
#pragma unroll
        for (int r = 0; r < 4; r++) {
            int node = nb + hrow0 + r;
            if (node < N_NODES) out[(size_t)node * D_INF + d] = acc[r] + bv;
        }
    }
}

// ---------------------------------------------------------------------------
// Fallback path (ws too small): atomic scatter + standalone MLP (proven r8).
// ---------------------------------------------------------------------------

#define W1_LD 72
#define W2_LD 136

__global__ void __launch_bounds__(256) mlp_mfma_kernel(
    const ushort* __restrict__ aggb, const ushort* __restrict__ w1tb,
    const float* __restrict__ b1v, const ushort* __restrict__ w2tb,
    const float* __restrict__ b2v, float* __restrict__ out)
{
    __shared__ __align__(16) ushort atile[64 * AT_LD];
    __shared__ __align__(16) ushort w1s[128 * W1_LD];
    __shared__ __align__(16) ushort w2s[64 * W2_LD];
    __shared__ __align__(16) ushort htile[64 * HT_LD];

    int tid = threadIdx.x;
    int lane = tid & 63;
    int wv = tid >> 6;
    int nb = blockIdx.x * 64;

#pragma unroll
    for (int c = 0; c < 2; c++) {
        int chunk = tid + c * 256;
        int row = chunk >> 3;
        int col = (chunk & 7) * 8;
        ulonglong2 v;
        v.x = 0; v.y = 0;
        if (nb + row < N_NODES)
            v = *reinterpret_cast<const ulonglong2*>(aggb + (size_t)(nb + row) * D_INF + col);
        *reinterpret_cast<ulonglong2*>(&atile[row * AT_LD + col]) = v;
    }
#pragma unroll
    for (int c = 0; c < 4; c++) {
        int chunk = tid + c * 256;
        int row = chunk >> 3;
        int col = (chunk & 7) * 8;
        *reinterpret_cast<ulonglong2*>(&w1s[row * W1_LD + col]) =
            *reinterpret_cast<const ulonglong2*>(w1tb + row * 64 + col);
    }
#pragma unroll
    for (int c = 0; c < 4; c++) {
        int chunk = tid + c * 256;
        int row = chunk >> 4;
        int col = (chunk & 15) * 8;
        *reinterpret_cast<ulonglong2*>(&w2s[row * W2_LD + col]) =
            *reinterpret_cast<const ulonglong2*>(w2tb + row * 128 + col);
    }
    __syncthreads();

    int q = lane >> 4;
    int m = lane & 15;
    int arow = wv * 16 + m;
    int hrow0 = wv * 16 + q * 4;

    bf16x8v a0 = *reinterpret_cast<const bf16x8v*>(&atile[arow * AT_LD + q * 8]);
    bf16x8v a1 = *reinterpret_cast<const bf16x8v*>(&atile[arow * AT_LD + 32 + q * 8]);
#pragma unroll
    for (int jt = 0; jt < 8; jt++) {
        int j = jt * 16 + m;
        bf16x8v bf0 = *reinterpret_cast<const bf16x8v*>(&w1s[j * W1_LD + q * 8]);
        bf16x8v bf1 = *reinterpret_cast<const bf16x8v*>(&w1s[j * W1_LD + 32 + q * 8]);
        f32x4 acc = {0.f, 0.f, 0.f, 0.f};
        acc = __builtin_amdgcn_mfma_f32_16x16x32_bf16(a0, bf0, acc, 0, 0, 0);
        acc = __builtin_amdgcn_mfma_f32_16x16x32_bf16(a1, bf1, acc, 0, 0, 0);
        float bv = b1v[j];
#pragma unroll
        for (int r = 0; r < 4; r++) {
            float hv = fmaxf(acc[r] + bv, 0.f);
            htile[(hrow0 + r) * HT_LD + j] = f2bf(hv);
        }
    }

    bf16x8v ha0 = *reinterpret_cast<const bf16x8v*>(&htile[arow * HT_LD + 0 * 32 + q * 8]);
    bf16x8v ha1 = *reinterpret_cast<const bf16x8v*>(&htile[arow * HT_LD + 1 * 32 + q * 8]);
    bf16x8v ha2 = *reinterpret_cast<const bf16x8v*>(&htile[arow * HT_LD + 2 * 32 + q * 8]);
    bf16x8v ha3 = *reinterpret_cast<const bf16x8v*>(&htile[arow * HT_LD + 3 * 32 + q * 8]);
#pragma unroll
    for (int dt = 0; dt < 4; dt++) {
        int d = dt * 16 + m;
        f32x4 acc = {0.f, 0.f, 0.f, 0.f};
        bf16x8v bw0 = *reinterpret_cast<const bf16x8v*>(&w2s[d * W2_LD + 0 * 32 + q * 8]);
        bf16x8v bw1 = *reinterpret_cast<const bf16x8v*>(&w2s[d * W2_LD + 1 * 32 + q * 8]);
        bf16x8v bw2 = *reinterpret_cast<const bf16x8v*>(&w2s[d * W2_LD + 2 * 32 + q * 8]);
        bf16x8v bw3 = *reinterpret_cast<const bf16x8v*>(&w2s[d * W2_LD + 3 * 32 + q * 8]);
        acc = __builtin_amdgcn_mfma_f32_16x16x32_bf16(ha0, bw0, acc, 0, 0, 0);
        acc = __builtin_amdgcn_mfma_f32_16x16x32_bf16(ha1, bw1, acc, 0, 0, 0);
        acc = __builtin_amdgcn_mfma_f32_16x16x32_bf16(ha2, bw2, acc, 0, 0, 0);
        acc = __builtin_amdgcn_mfma_f32_16x16x32_bf16(ha3, bw3, acc, 0, 0, 0);
        float bv = b2v[d];
#pragma unroll
        for (int r = 0; r < 4; r++) {
            int node = nb + hrow0 + r;
            if (node < N_NODES) out[(size_t)node * D_INF + d] = acc[r] + bv;
        }
    }
}

__global__ void init_agg_kernel(const float* __restrict__ x, float* __restrict__ agg) {
    int i = blockIdx.x * blockDim.x + threadIdx.x;
    int n4 = N_NODES * D_INF / 4;
    if (i < n4) {
        reinterpret_cast<float4*>(agg)[i] = reinterpret_cast<const float4*>(x)[i];
    }
}

__global__ void scatter_kernel(const float* __restrict__ x,
                               const int* __restrict__ src,
                               const int* __restrict__ dst,
                               float* __restrict__ agg) {
    int tid = blockIdx.x * blockDim.x + threadIdx.x;
    int e = tid >> 6;
    int d = tid & 63;
    if (e < N_EDGES) {
        atomicAdd(&agg[(size_t)dst[e] * D_INF + d], x[(size_t)src[e] * D_INF + d]);
    }
}

__global__ void cvt_agg_kernel(const float* __restrict__ agg32, ushort* __restrict__ aggb) {
    int i = blockIdx.x * blockDim.x + threadIdx.x;
    if (i < N_NODES * D_INF) aggb[i] = f2bf(agg32[i]);
}

__global__ void prep_weights_only_kernel(const float* __restrict__ W1,
                                         const float* __restrict__ W2,
                                         ushort* __restrict__ w1tb,
                                         ushort* __restrict__ w2tb) {
    int i = blockIdx.x * blockDim.x + threadIdx.x;
    if (i < D_INF * D_HIDF) {
        int j = i >> 6, l = i & 63;
        w1tb[i] = f2bf(W1[l * D_HIDF + j]);
        int d = i >> 7, jj = i & 127;
        w2tb[i] = f2bf(W2[jj * D_INF + d]);
    }
}

// ---------------------------------------------------------------------------

extern "C" void kernel_launch(void* const* d_in, const int* in_sizes, int n_in,
                              void* d_out, int out_size, void* d_ws, size_t ws_size,
                              hipStream_t stream) {
    const float* x   = (const float*)d_in[0];
    const int* edge  = (const int*)d_in[1];   // [2, E]: src = edge, dst = edge + E
    const float* W1  = (const float*)d_in[2];
    const float* b1  = (const float*)d_in[3];
    const float* W2  = (const float*)d_in[4];
    const float* b2  = (const float*)d_in[5];
    float* out       = (float*)d_out;

    const int* src = edge;
    const int* dst = edge + N_EDGES;

    // Workspace layout (fast path ~19.3 MB):
    //   w1tb / w2tb : 8192 bf16 each (32 KB)
    //   xb     : (N+1)*64 bf16 (6.4 MB, incl. zero row at N_NODES)
    //   gcursor: NBUCKET ints
    //   binned : NBUCKET*CAP uints (12.8 MB)
    //   fallback overlay: agg32 (f32, at xb) + aggb (bf16, after binned)
    ushort* w1tb   = (ushort*)d_ws;
    ushort* w2tb   = w1tb + D_INF * D_HIDF;
    ushort* xb     = w2tb + D_INF * D_HIDF;
    int* gcursor   = (int*)(xb + (size_t)(N_NODES + 1) * D_INF);
    unsigned int* binned = (unsigned int*)(gcursor + NBUCKET);
    float* agg32   = (float*)xb;
    ushort* aggb   = (ushort*)(binned + (size_t)NBUCKET * CAP);

    size_t needed_full = (uintptr_t)(binned + (size_t)NBUCKET * CAP) - (uintptr_t)d_ws;
    size_t needed_fb   = (uintptr_t)(aggb + (size_t)N_NODES * D_INF) - (uintptr_t)d_ws;

    if (ws_size >= needed_full) {
        init_gcursor_kernel<<<(NBUCKET + 255) / 256, 256, 0, stream>>>(gcursor);
        sortfill_cvt_kernel<<<NCHUNK + CVT_BLKS, 512, 0, stream>>>(
            src, dst, gcursor, binned, x, xb, W1, W2, w1tb, w2tb);
        mega_kernel<<<NBUCKET, 1024, 0, stream>>>(
            xb, binned, gcursor, w1tb, b1, w2tb, b2, out);
    } else if (ws_size >= needed_fb) {
        prep_weights_only_kernel<<<(PREP_N + 255) / 256, 256, 0, stream>>>(W1, W2, w1tb, w2tb);
        int n4 = N_NODES * D_INF / 4;
        init_agg_kernel<<<(n4 + 255) / 256, 256, 0, stream>>>(x, agg32);
        int work = N_EDGES * D_INF;
        scatter_kernel<<<(work + 255) / 256, 256, 0, stream>>>(x, src, dst, agg32);
        cvt_agg_kernel<<<(N_NODES * D_INF + 255) / 256, 256, 0, stream>>>(agg32, aggb);
        mlp_mfma_kernel<<<(N_NODES + 63) / 64, 256, 0, stream>>>(aggb, w1tb, b1, w2tb, b2, out);
    }
}